// Round 1
// baseline (67.526 us; speedup 1.0000x reference)
//
#include <hip/hip_runtime.h>

// HexaToParallelogram: out[b, cell] = idx[cell] >= 0 ? hexa[b, idx[cell]] : 0.0f
// B = 32768 rows, NP = 1039 hex pixels/row, P = 31*39 = 1209 dense cells/row.
// Pure memory-bound gather: ~295 MB traffic -> ~47 us floor at 6.3 TB/s.

constexpr int NP = 1039;   // NUM_PIXELS
constexpr int P  = 1209;   // (2*q_max+1) * (2*r_max+1) = 31 * 39

__global__ void hexa_gather_vec4(const float* __restrict__ hexa,
                                 const int* __restrict__ gidx,
                                 float4* __restrict__ out4,
                                 int nvec) {
  __shared__ int sidx[P];
  for (int t = threadIdx.x; t < P; t += blockDim.x) sidx[t] = gidx[t];
  __syncthreads();

  const int stride = gridDim.x * blockDim.x;
  for (int v = blockIdx.x * blockDim.x + threadIdx.x; v < nvec; v += stride) {
    int i = v * 4;              // flat output element index (< 2^31)
    int b = i / P;              // constant divisor -> magic-mul, no v_div
    int p = i - b * P;
    const float* src = hexa + (size_t)b * NP;
    float4 r;
    float* rp = reinterpret_cast<float*>(&r);
#pragma unroll
    for (int j = 0; j < 4; ++j) {
      int id = sidx[p];
      rp[j] = (id >= 0) ? src[id] : 0.0f;
      if (++p == P) { p = 0; src += NP; }   // cross row boundary (P odd)
    }
    out4[v] = r;
  }
}

// Safety net only: runtime-P scalar path in case grid-shape derivation is off.
__global__ void hexa_gather_rt(const float* __restrict__ hexa,
                               const int* __restrict__ gidx,
                               float* __restrict__ out,
                               int n, int Prt) {
  extern __shared__ int sidx[];
  for (int t = threadIdx.x; t < Prt; t += blockDim.x) sidx[t] = gidx[t];
  __syncthreads();
  const int stride = gridDim.x * blockDim.x;
  for (int i = blockIdx.x * blockDim.x + threadIdx.x; i < n; i += stride) {
    int b = i / Prt;
    int p = i - b * Prt;
    int id = sidx[p];
    out[i] = (id >= 0) ? hexa[(size_t)b * NP + id] : 0.0f;
  }
}

extern "C" void kernel_launch(void* const* d_in, const int* in_sizes, int n_in,
                              void* d_out, int out_size, void* d_ws, size_t ws_size,
                              hipStream_t stream) {
  const float* hexa = (const float*)d_in[0];
  const int*   gidx = (const int*)d_in[1];
  const int block = 256;

  if (in_sizes[1] == P && (out_size & 3) == 0) {
    int nvec = out_size >> 2;
    int grid = (nvec + block - 1) / block;
    if (grid > 2048) grid = 2048;   // grid-stride; ~8 blocks/CU
    hexa_gather_vec4<<<grid, block, 0, stream>>>(hexa, gidx, (float4*)d_out, nvec);
  } else {
    int Prt = in_sizes[1];
    int grid = (out_size + block - 1) / block;
    if (grid > 2048) grid = 2048;
    hexa_gather_rt<<<grid, block, (size_t)Prt * sizeof(int), stream>>>(
        hexa, gidx, (float*)d_out, out_size, Prt);
  }
}

// Round 2
// 55.928 us; speedup vs baseline: 1.2074x; 1.2074x over previous
//
#include <hip/hip_runtime.h>

// HexaToParallelogram: out[b, cell] = idx[cell] >= 0 ? hexa[b, idx[cell]] : 0.0f
// B = 32768, NP = 1039 hex pixels/row, P = 31*39 = 1209 dense cells/row.
// Memory-bound: ~295 MB traffic -> ~45 us floor at the ~6.8-7 TB/s the harness
// fill kernels demonstrate.
//
// R1 layout change: consecutive lanes own consecutive output elements (vec2
// granularity). Gather reads coalesce (lane-stride 8B), LDS index lookups are
// stride-2 (4-way conflict = 1.58x, only 2/iter), stores are dwordx2.

constexpr int NP = 1039;   // NUM_PIXELS
constexpr int P  = 1209;   // (2*q_max+1) * (2*r_max+1) = 31 * 39

__global__ void hexa_gather_vec2(const float* __restrict__ hexa,
                                 const int* __restrict__ gidx,
                                 float2* __restrict__ out2,
                                 int nvec) {
  __shared__ int sidx[P];
  for (int t = threadIdx.x; t < P; t += blockDim.x) sidx[t] = gidx[t];
  __syncthreads();

  const int stride = gridDim.x * blockDim.x;
  for (int v = blockIdx.x * blockDim.x + threadIdx.x; v < nvec; v += stride) {
    int i = v * 2;              // flat output element index
    int b = i / P;              // constant divisor -> magic-mul
    int p = i - b * P;
    const float* src = hexa + (size_t)b * NP;

    float2 r;
    int id0 = sidx[p];
    r.x = (id0 >= 0) ? src[id0] : 0.0f;
    ++p;
    if (p == P) { p = 0; src += NP; }   // pair crosses b-row (P odd)
    int id1 = sidx[p];
    r.y = (id1 >= 0) ? src[id1] : 0.0f;

    out2[v] = r;
  }
}

// Safety net: runtime-P scalar path in case grid-shape derivation is off.
__global__ void hexa_gather_rt(const float* __restrict__ hexa,
                               const int* __restrict__ gidx,
                               float* __restrict__ out,
                               int n, int Prt) {
  extern __shared__ int sidx[];
  for (int t = threadIdx.x; t < Prt; t += blockDim.x) sidx[t] = gidx[t];
  __syncthreads();
  const int stride = gridDim.x * blockDim.x;
  for (int i = blockIdx.x * blockDim.x + threadIdx.x; i < n; i += stride) {
    int b = i / Prt;
    int p = i - b * Prt;
    int id = sidx[p];
    out[i] = (id >= 0) ? hexa[(size_t)b * NP + id] : 0.0f;
  }
}

extern "C" void kernel_launch(void* const* d_in, const int* in_sizes, int n_in,
                              void* d_out, int out_size, void* d_ws, size_t ws_size,
                              hipStream_t stream) {
  const float* hexa = (const float*)d_in[0];
  const int*   gidx = (const int*)d_in[1];
  const int block = 256;

  if (in_sizes[1] == P && (out_size & 1) == 0) {
    int nvec = out_size >> 1;
    int grid = (nvec + block - 1) / block;
    if (grid > 2048) grid = 2048;   // 8 blocks/CU * 4 waves = full 32 waves/CU
    hexa_gather_vec2<<<grid, block, 0, stream>>>(hexa, gidx, (float2*)d_out, nvec);
  } else {
    int Prt = in_sizes[1];
    int grid = (out_size + block - 1) / block;
    if (grid > 2048) grid = 2048;
    hexa_gather_rt<<<grid, block, (size_t)Prt * sizeof(int), stream>>>(
        hexa, gidx, (float*)d_out, out_size, Prt);
  }
}